// Round 9
// baseline (344.457 us; speedup 1.0000x reference)
//
#include <hip/hip_runtime.h>

#define B_TOTAL 262144
#define K_CB    512
#define D_DIM   3
#define BLOCK   256
#define MAGIC   0x1234ABCDu

// monotone map fp32 bits -> uint32 (ascending float => ascending uint)
__device__ __forceinline__ unsigned int mono32(unsigned int u) {
    unsigned int m = (u & 0x80000000u) ? 0xFFFFFFFFu : 0x80000000u;
    return u ^ m;
}

// Fused: blocks 0..5 rank-sort the codebook into d_ws and release per-builder
// flags; ALL 1024 blocks (co-resident by capacity: 12KB LDS, 256 thr, ~48 VGPR
// => 8 blocks/CU * 256 CU = 2048 slots >= 1024, so builders can never be
// starved) acquire-spin on the flags, stage the tables to LDS, then run the
// validated binary-search + tie-break. One dispatch: no inter-kernel L2
// flush/launch gap.
__global__ __launch_bounds__(BLOCK) void vq_fused_kernel(
    const float* __restrict__ ze, const float* __restrict__ e,
    float* __restrict__ ws_val, int* __restrict__ ws_idx,
    unsigned int* __restrict__ flags,
    float* __restrict__ z_out, float* __restrict__ zq_out)
{
    __shared__ __align__(16) unsigned char smem[12288];
    const int tid = threadIdx.x;

    // ---------------- builder phase: blocks 0..5 ----------------
    if (blockIdx.x < D_DIM * 2) {
        unsigned long long* key = (unsigned long long*)smem;   // 4 KB
        float*              val = (float*)(smem + 4096);       // 2 KB

        const int d    = blockIdx.x >> 1;
        const int half = blockIdx.x & 1;

        for (int k = tid; k < K_CB; k += BLOCK) {
            float v = e[k * D_DIM + d];
            key[k] = ((unsigned long long)mono32(__float_as_uint(v)) << 32)
                   | (unsigned int)k;
            val[k] = v;
        }
        __syncthreads();

        const int i = half * BLOCK + tid;
        const unsigned long long mykey = key[i];
        int rank = 0;
        #pragma unroll 8
        for (int j = 0; j < K_CB; ++j)          // wave-uniform LDS: broadcast
            rank += (key[j] < mykey) ? 1 : 0;

        ws_val[d * K_CB + rank] = val[i];       // stable (value, idx) order
        ws_idx[d * K_CB + rank] = i;

        __threadfence();                        // agent-scope release (L2 wb)
        __syncthreads();                        // all table stores fenced
        if (tid == 0)
            __hip_atomic_store(&flags[blockIdx.x], MAGIC,
                               __ATOMIC_RELEASE, __HIP_MEMORY_SCOPE_AGENT);
        __syncthreads();                        // smem reuse safe below
    }

    // ---------------- wait for all 6 builders ----------------
    for (int f = 0; f < D_DIM * 2; ++f) {
        while (__hip_atomic_load(&flags[f], __ATOMIC_ACQUIRE,
                                 __HIP_MEMORY_SCOPE_AGENT) != MAGIC)
            __builtin_amdgcn_s_sleep(8);        // ~512 cy poll period
    }

    // ---------------- search phase (R8's validated K2) ----------------
    float (*sval)[K_CB] = (float (*)[K_CB])smem;          // [3][512] 6 KB
    int   (*sidx)[K_CB] = (int   (*)[K_CB])(smem + 6144); // [3][512] 6 KB

    {   // vectorized staging
        const float4* gv = (const float4*)ws_val; float4* lv = (float4*)sval;
        for (int i = tid; i < D_DIM * K_CB / 4; i += BLOCK) lv[i] = gv[i];
        const int4*   gi = (const int4*)ws_idx;   int4*   li = (int4*)sidx;
        for (int i = tid; i < D_DIM * K_CB / 4; i += BLOCK) li[i] = gi[i];
    }
    __syncthreads();

    const int b = blockIdx.x * BLOCK + tid;
    const float xs[D_DIM] = { ze[b * 3 + 0], ze[b * 3 + 1], ze[b * 3 + 2] };

    #pragma unroll
    for (int d = 0; d < D_DIM; ++d) {
        const float xv = xs[d];

        // binary search: invariant sval[lo] <= xv < sval[hi] (virtual
        // sentinels -1/512); 10 iters fully resolve the 513-state interval
        int lo = -1, hi = K_CB;
        #pragma unroll
        for (int it = 0; it < 10; ++it) {
            int mid = (lo + hi) >> 1;
            bool le = sval[d][mid] <= xv;
            lo = le ? mid : lo;
            hi = le ? hi : mid;
        }

        // left candidate: walk back to head of equal-value run (min orig idx)
        float dl = 3.402823466e38f, vl = 0.0f; int il = 0;
        if (lo >= 0) {
            vl = sval[d][lo];
            int p = lo;
            while (p > 0 && sval[d][p - 1] == vl) --p;
            il = sidx[d][p];
            float t = xv - vl;                  // identical fp32 arith to ref
            dl = t * t;
        }
        // right candidate: nearest value > xv (group head == lo+1)
        float dr = 3.402823466e38f, vr = 0.0f; int ir = 0;
        if (lo < K_CB - 1) {
            vr = sval[d][lo + 1];
            ir = sidx[d][lo + 1];
            float t = xv - vr;
            dr = t * t;
        }

        // np.argmin semantics: strict min; tie -> smaller original index
        const bool pickR = (dr < dl) || ((dr == dl) && (ir < il));
        z_out [b * 3 + d] = (float)(pickR ? ir : il);
        zq_out[b * 3 + d] = pickR ? vr : vl;
    }
}

extern "C" void kernel_launch(void* const* d_in, const int* in_sizes, int n_in,
                              void* d_out, int out_size, void* d_ws, size_t ws_size,
                              hipStream_t stream) {
    const float* ze = (const float*)d_in[0];
    const float* e  = (const float*)d_in[1];
    float* z_out  = (float*)d_out;                    // z  : B*D float32
    float* zq_out = z_out + (size_t)B_TOTAL * D_DIM;  // zq : B*D float32

    float*        ws_val = (float*)d_ws;                   // [3][512]
    int*          ws_idx = (int*)(ws_val + D_DIM * K_CB);  // [3][512]
    unsigned int* flags  = (unsigned int*)((char*)d_ws + 12288); // 6 u32
    // flags re-poisoned to 0xAAAAAAAA (!= MAGIC) before every launch by the
    // harness => same work every call, graph-replay safe.

    vq_fused_kernel<<<B_TOTAL / BLOCK, BLOCK, 0, stream>>>(
        ze, e, ws_val, ws_idx, flags, z_out, zq_out);
}

// Round 10
// 71.997 us; speedup vs baseline: 4.7843x; 4.7843x over previous
//
#include <hip/hip_runtime.h>

#define B_TOTAL 262144
#define K_CB    512
#define D_DIM   3
#define BLOCK   256
#define NSLOT   (B_TOTAL * D_DIM)          // 786432 flat scalar slots

// monotone map fp32 bits -> uint32 (ascending float => ascending uint)
__device__ __forceinline__ unsigned int mono32(unsigned int u) {
    unsigned int m = (u & 0x80000000u) ? 0xFFFFFFFFu : 0x80000000u;
    return u ^ m;
}

// ---------------- kernel 1: rank-sort the tiny codebook into d_ws ------------
// (byte-identical to R8's validated K1)
__global__ __launch_bounds__(BLOCK) void rank_kernel(
    const float* __restrict__ e, float* __restrict__ ws_val, int* __restrict__ ws_idx)
{
    const int d    = blockIdx.x >> 1;
    const int half = blockIdx.x & 1;
    const int tid  = threadIdx.x;

    __shared__ unsigned long long key[K_CB];
    __shared__ float              val[K_CB];

    for (int k = tid; k < K_CB; k += BLOCK) {
        float v = e[k * D_DIM + d];
        key[k] = ((unsigned long long)mono32(__float_as_uint(v)) << 32) | (unsigned int)k;
        val[k] = v;
    }
    __syncthreads();

    const int i = half * BLOCK + tid;
    const unsigned long long mykey = key[i];
    int rank = 0;
    #pragma unroll 8
    for (int j = 0; j < K_CB; ++j)              // wave-uniform LDS reads: broadcast
        rank += (key[j] < mykey) ? 1 : 0;

    ws_val[d * K_CB + rank] = val[i];
    ws_idx[d * K_CB + rank] = i;
}

// ---------------- kernel 2: slot-mapped search, float4 I/O -------------------
// Each thread owns 4 CONSECUTIVE flat slots (slot = b*3+d): 1 float4 load,
// 2 float4 stores, all aligned & fully coalesced. Search logic per slot is
// the validated 10-iter binary search + duplicate walk + tie rule.
__global__ __launch_bounds__(BLOCK) void vq_search_kernel(
    const float* __restrict__ ze,
    const float* __restrict__ ws_val, const int* __restrict__ ws_idx,
    float* __restrict__ z_out, float* __restrict__ zq_out)
{
    __shared__ float sval[D_DIM * K_CB];   // 6 KB, [d*512 + pos]
    __shared__ int   sidx[D_DIM * K_CB];   // 6 KB

    const int tid = threadIdx.x;
    {   // vectorized staging
        const float4* gv = (const float4*)ws_val; float4* lv = (float4*)sval;
        for (int i = tid; i < D_DIM * K_CB / 4; i += BLOCK) lv[i] = gv[i];
        const int4*   gi = (const int4*)ws_idx;   int4*   li = (int4*)sidx;
        for (int i = tid; i < D_DIM * K_CB / 4; i += BLOCK) li[i] = gi[i];
    }
    __syncthreads();

    const int s4 = (blockIdx.x * BLOCK + tid) * 4;    // first of my 4 slots
    const float4 xv4 = *(const float4*)(ze + s4);
    const float xs[4] = { xv4.x, xv4.y, xv4.z, xv4.w };

    // dims of the 4 consecutive slots: d0 = s4 % 3, then +1 mod 3 each
    const int d0 = s4 % 3;
    int dcur = d0;
    float zz[4], zq[4];

    #pragma unroll
    for (int q = 0; q < 4; ++q) {
        const int base = dcur * K_CB;
        dcur = (dcur == 2) ? 0 : dcur + 1;
        const float xv = xs[q];

        // binary search: invariant sval[lo] <= xv < sval[hi] (virtual
        // sentinels -1/512); 10 iters fully resolve the 513-state interval
        int lo = -1, hi = K_CB;
        #pragma unroll
        for (int it = 0; it < 10; ++it) {
            int mid = (lo + hi) >> 1;
            bool le = sval[base + mid] <= xv;
            lo = le ? mid : lo;
            hi = le ? hi : mid;
        }

        // left candidate: walk back to head of equal-value run (min orig idx)
        float dl = 3.402823466e38f, vl = 0.0f; int il = 0;
        if (lo >= 0) {
            vl = sval[base + lo];
            int p = lo;
            while (p > 0 && sval[base + p - 1] == vl) --p;
            il = sidx[base + p];
            float t = xv - vl;                  // identical fp32 arith to ref
            dl = t * t;
        }
        // right candidate: nearest value > xv (group head == lo+1)
        float dr = 3.402823466e38f, vr = 0.0f; int ir = 0;
        if (lo < K_CB - 1) {
            vr = sval[base + lo + 1];
            ir = sidx[base + lo + 1];
            float t = xv - vr;
            dr = t * t;
        }

        // np.argmin semantics: strict min; tie -> smaller original index
        const bool pickR = (dr < dl) || ((dr == dl) && (ir < il));
        zz[q] = (float)(pickR ? ir : il);
        zq[q] = pickR ? vr : vl;
    }

    *(float4*)(z_out  + s4) = make_float4(zz[0], zz[1], zz[2], zz[3]);
    *(float4*)(zq_out + s4) = make_float4(zq[0], zq[1], zq[2], zq[3]);
}

extern "C" void kernel_launch(void* const* d_in, const int* in_sizes, int n_in,
                              void* d_out, int out_size, void* d_ws, size_t ws_size,
                              hipStream_t stream) {
    const float* ze = (const float*)d_in[0];
    const float* e  = (const float*)d_in[1];
    float* z_out  = (float*)d_out;                    // z  : B*D float32
    float* zq_out = z_out + (size_t)NSLOT;            // zq : B*D float32

    float* ws_val = (float*)d_ws;                     // [3][512] sorted values
    int*   ws_idx = (int*)(ws_val + D_DIM * K_CB);    // [3][512] original indices

    rank_kernel     <<<D_DIM * 2,         BLOCK, 0, stream>>>(e, ws_val, ws_idx);
    vq_search_kernel<<<NSLOT / (4 * BLOCK), BLOCK, 0, stream>>>(ze, ws_val, ws_idx,
                                                                z_out, zq_out);
}